// Round 5
// baseline (46.030 us; speedup 1.0000x reference)
//
#include <hip/hip_runtime.h>
#include <cstddef>
#include <type_traits>

#define BB 2
#define TT 4
#define LL 384
#define CZ 128
#define NBINS 39
#define NBOUND 38

typedef float f32x4 __attribute__((ext_vector_type(4)));

// One block per (b, i). 512 threads. NO weight staging: weight (42 KB) is
// shared by all 768 blocks -> L1/L2-resident; gather rows directly from
// global. LDS = per-j meta only (6 KB).
__global__ __launch_bounds__(512) void tpe_kernel(
    const int*   __restrict__ aatype,   // [B,T,L] int32
    const float* __restrict__ coords,   // [B,T,L,3] f32
    const int*   __restrict__ tmask,    // [B,T,L] bool->int32
    const int*   __restrict__ rmask,    // [B,L] bool->int32
    const float* __restrict__ weight,   // [82,128] f32
    const float* __restrict__ bias,     // [128] f32
    float*       __restrict__ out)      // [B,L,L,128] f32
{
    __shared__ int4 meta_sh[LL];        // {pk01, pk23, 0, scale}; pk: bin|aa<<6|act<<11

    const int bi  = blockIdx.x;
    const int b   = bi / LL;
    const int i   = bi - b * LL;
    const int tid = threadIdx.x;
    const int bT  = b * TT;

    // Block-uniform i-activity code.
    int icode = 0;
    #pragma unroll
    for (int t = 0; t < TT; ++t)
        icode |= (tmask[(bT + t) * LL + i] != 0) << t;

    // ---- Phase 1: per-j meta (one thread per j) ----
    if (tid < LL) {
        #pragma clang fp contract(off)
        const int j  = tid;
        const int ri = rmask[b * LL + i];
        unsigned pks[TT] = {0, 0, 0, 0};
        int cnt = 0;
        #pragma unroll
        for (int t = 0; t < TT; ++t) {
            if (icode & (1 << t)) {                 // wave-uniform branch
                const int base = (bT + t) * LL;
                if (tmask[base + j] != 0) {
                    const float* ci = coords + (size_t)(base + i) * 3;
                    const float* cj = coords + (size_t)(base + j) * 3;
                    float dx = ci[0] - cj[0];
                    float dy = ci[1] - cj[1];
                    float dz = ci[2] - cj[2];
                    float s  = dx * dx + dy * dy;   // numpy order ((x+y)+z)
                    s = s + dz * dz;
                    float d = sqrtf(s);             // IEEE sqrt
                    int bin = 0;
                    #pragma unroll
                    for (int k = 0; k < NBOUND; ++k) {
                        // folded at compile time; matches np.linspace(f64).astype(f32)
                        float bnd = (float)(3.25 + (double)k * (47.5 / 37.0));
                        bin += (d > bnd) ? 1 : 0;   // searchsorted side='left'
                    }
                    int aa = aatype[base + j];
                    aa = min(max(aa, 0), 20);
                    pks[t] = (unsigned)(bin | (aa << 6) | (1 << 11));
                    ++cnt;
                }
            }
        }
        float scale = (ri != 0 && rmask[b * LL + j] != 0)
                      ? 1.0f / fmaxf((float)cnt, 1.0f) : 0.0f;
        int4 m;
        m.x = (int)(pks[0] | (pks[1] << 16));
        m.y = (int)(pks[2] | (pks[3] << 16));
        m.z = 0;
        m.w = __float_as_int(scale);
        meta_sh[j] = m;
    }
    __syncthreads();

    // ---- Phase 2: gathers straight from global (L1/L2-hot weight) ----
    const int cg = tid & 31;       // channel group (4 channels)
    const int jj = tid >> 5;       // 0..15
    const f32x4* W4 = (const f32x4*)weight;   // row r at W4[r*32 + cg]
    const f32x4* B4 = (const f32x4*)bias;
    const f32x4 wmb = W4[NBINS * (CZ / 4) + cg] + B4[cg];   // W_m + bias
    f32x4* outv = (f32x4*)(out + (size_t)(b * LL + i) * LL * CZ);

    auto run = [&](auto cmc) {
        constexpr int CM = decltype(cmc)::value;
        f32x4 pr[TT];
        #pragma unroll
        for (int t = 0; t < TT; ++t)
            if (CM & (1 << t)) {
                int aa = aatype[(bT + t) * LL + i];
                aa = min(max(aa, 0), 20);
                pr[t] = W4[(NBINS + 1 + aa) * (CZ / 4) + cg] + wmb;  // W_i + W_m + bias
            }
        #pragma unroll 4
        for (int j = jj; j < LL; j += 16) {
            int4 m = meta_sh[j];                    // broadcast b128
            f32x4 acc = {0.f, 0.f, 0.f, 0.f};
            #pragma unroll
            for (int t = 0; t < TT; ++t) {
                if (CM & (1 << t)) {
                    unsigned h = (unsigned)(t < 2 ? m.x : m.y);
                    unsigned pk = (h >> ((t & 1) * 16)) & 0xFFFFu;
                    f32x4 a = W4[(pk & 63u) * (CZ / 4) + cg];                   // W_d[bin]
                    f32x4 c = W4[(NBINS + 22 + ((pk >> 6) & 31u)) * (CZ / 4) + cg]; // W_j[aa]
                    float mt = (float)((pk >> 11) & 1u);
                    acc += (a + c + pr[t]) * mt;
                }
            }
            outv[j * (CZ / 4) + cg] = acc * __int_as_float(m.w);
        }
    };

    #define RUN_CASE(K) case K: run(std::integral_constant<int, K>{}); break;
    switch (icode) {
        RUN_CASE(0)  RUN_CASE(1)  RUN_CASE(2)  RUN_CASE(3)
        RUN_CASE(4)  RUN_CASE(5)  RUN_CASE(6)  RUN_CASE(7)
        RUN_CASE(8)  RUN_CASE(9)  RUN_CASE(10) RUN_CASE(11)
        RUN_CASE(12) RUN_CASE(13) RUN_CASE(14) RUN_CASE(15)
    }
    #undef RUN_CASE
}

extern "C" void kernel_launch(void* const* d_in, const int* in_sizes, int n_in,
                              void* d_out, int out_size, void* d_ws, size_t ws_size,
                              hipStream_t stream) {
    const int*   aatype = (const int*)d_in[0];
    const float* coords = (const float*)d_in[1];
    const int*   tmask  = (const int*)d_in[2];
    const int*   rmask  = (const int*)d_in[3];
    const float* weight = (const float*)d_in[4];
    const float* bias   = (const float*)d_in[5];
    float* out = (float*)d_out;

    dim3 grid(BB * LL);
    dim3 block(512);
    tpe_kernel<<<grid, block, 0, stream>>>(aatype, coords, tmask, rmask, weight, bias, out);
}

// Round 6
// 39.313 us; speedup vs baseline: 1.1709x; 1.1709x over previous
//
#include <hip/hip_runtime.h>
#include <cstddef>
#include <type_traits>

#define BB 2
#define TT 4
#define LL 384
#define CZ 128
#define NBINS 39
#define NBOUND 38
#define NSL 3          // row-blocks per persistent block

typedef float f32x4 __attribute__((ext_vector_type(4)));

// Persistent: 256 blocks x 512 threads, one block per CU. Each block stages
// weights ONCE, builds meta for its 3 (b,i) rows, ONE barrier, then three
// barrier-free store sweeps (store queue never drained mid-kernel).
// LDS: Wd' 19.5K + Wj 10.5K + meta 3x6K = 48 KB.
__global__ __launch_bounds__(512) void tpe_kernel(
    const int*   __restrict__ aatype,   // [B,T,L] int32
    const float* __restrict__ coords,   // [B,T,L,3] f32
    const int*   __restrict__ tmask,    // [B,T,L] bool->int32
    const int*   __restrict__ rmask,    // [B,L] bool->int32
    const float* __restrict__ weight,   // [82,128] f32
    const float* __restrict__ bias,     // [128] f32
    float*       __restrict__ out)      // [B,L,L,128] f32
{
    __shared__ float Wd_sh[NBINS * CZ];   // rows 0..38, pre-folded with (W_m + bias)
    __shared__ float Wj_sh[21 * CZ];      // rows 61..81
    __shared__ int4  meta_sh[NSL][LL];    // {pk01, pk23, 0, scale}; pk: bin|aa<<6|act<<11

    const int blk = blockIdx.x;
    const int tid = threadIdx.x;

    // ---- Stage Wd (+Wm+bias folded) and Wj into LDS (once) ----
    {
        const float4* wsrc = (const float4*)weight;
        const float4* bs4  = (const float4*)bias;
        float4* wd = (float4*)Wd_sh;
        float4* wj = (float4*)Wj_sh;
        #pragma unroll
        for (int k = 0; k < 4; ++k) {
            int idx = tid + k * 512;
            if (idx < 1248) {
                float4 w  = wsrc[idx];
                float4 wm = wsrc[NBINS * (CZ / 4) + (idx & 31)];
                float4 b4 = bs4[idx & 31];
                w.x += wm.x + b4.x; w.y += wm.y + b4.y;
                w.z += wm.z + b4.z; w.w += wm.w + b4.w;
                wd[idx] = w;
            } else if (idx < 1920) {
                wj[idx - 1248] = wsrc[61 * (CZ / 4) + (idx - 1248)];
            }
        }
    }

    // ---- Build meta for all NSL rows (1152 entries over 512 threads) ----
    {
        #pragma clang fp contract(off)
        for (int idx = tid; idx < NSL * LL; idx += 512) {
            const int s  = idx / LL;
            const int j  = idx - s * LL;
            const int bi = blk + s * 256;
            const int b  = bi / LL;
            const int i  = bi - b * LL;
            const int bT = b * TT;
            const int ri = rmask[b * LL + i];
            unsigned pks[TT] = {0, 0, 0, 0};
            int cnt = 0;
            #pragma unroll
            for (int t = 0; t < TT; ++t) {
                const int base = (bT + t) * LL;
                if (tmask[base + i] != 0 && tmask[base + j] != 0) {
                    const float* ci = coords + (size_t)(base + i) * 3;
                    const float* cj = coords + (size_t)(base + j) * 3;
                    float dx = ci[0] - cj[0];
                    float dy = ci[1] - cj[1];
                    float dz = ci[2] - cj[2];
                    float ss = dx * dx + dy * dy;   // numpy order ((x+y)+z)
                    ss = ss + dz * dz;
                    float d = sqrtf(ss);            // IEEE sqrt
                    int bin = 0;
                    #pragma unroll
                    for (int k = 0; k < NBOUND; ++k) {
                        // folded at compile time; matches np.linspace(f64).astype(f32)
                        float bnd = (float)(3.25 + (double)k * (47.5 / 37.0));
                        bin += (d > bnd) ? 1 : 0;   // searchsorted side='left'
                    }
                    int aa = aatype[base + j];
                    aa = min(max(aa, 0), 20);
                    pks[t] = (unsigned)(bin | (aa << 6) | (1 << 11));
                    ++cnt;
                }
            }
            float scale = (ri != 0 && rmask[b * LL + j] != 0)
                          ? 1.0f / fmaxf((float)cnt, 1.0f) : 0.0f;
            int4 m;
            m.x = (int)(pks[0] | (pks[1] << 16));
            m.y = (int)(pks[2] | (pks[3] << 16));
            m.z = 0;
            m.w = __float_as_int(scale);
            meta_sh[s][j] = m;
        }
    }
    __syncthreads();   // the ONLY barrier

    // ---- Three barrier-free sweeps ----
    const int cg = tid & 31;       // channel group (4 channels)
    const int jj = tid >> 5;       // 0..15
    const f32x4* Wd4 = (const f32x4*)Wd_sh;
    const f32x4* Wj4 = (const f32x4*)Wj_sh;
    const f32x4* W4  = (const f32x4*)weight;

    for (int s = 0; s < NSL; ++s) {
        const int bi = blk + s * 256;
        const int b  = bi / LL;
        const int i  = bi - b * LL;
        const int bT = b * TT;

        int icode = 0;
        #pragma unroll
        for (int t = 0; t < TT; ++t)
            icode |= (tmask[(bT + t) * LL + i] != 0) << t;

        const int4* meta = meta_sh[s];
        f32x4* outv = (f32x4*)(out + (size_t)(b * LL + i) * LL * CZ);

        auto run = [&](auto cmc) {
            constexpr int CM = decltype(cmc)::value;
            f32x4 pr[TT];
            #pragma unroll
            for (int t = 0; t < TT; ++t)
                if (CM & (1 << t)) {
                    int aa = aatype[(bT + t) * LL + i];
                    aa = min(max(aa, 0), 20);
                    pr[t] = W4[(NBINS + 1 + aa) * (CZ / 4) + cg];  // W_i (global, L2-hot)
                }
            #pragma unroll 4
            for (int j = jj; j < LL; j += 16) {
                int4 m = meta[j];                   // broadcast b128
                f32x4 acc = {0.f, 0.f, 0.f, 0.f};
                #pragma unroll
                for (int t = 0; t < TT; ++t) {
                    if (CM & (1 << t)) {
                        unsigned h = (unsigned)(t < 2 ? m.x : m.y);
                        unsigned pk = (h >> ((t & 1) * 16)) & 0xFFFFu;
                        f32x4 a = Wd4[(pk & 63u) * (CZ / 4) + cg];        // Wd+Wm+bias
                        f32x4 c = Wj4[((pk >> 6) & 31u) * (CZ / 4) + cg]; // Wj
                        float mt = (float)((pk >> 11) & 1u);
                        acc += (a + c + pr[t]) * mt;
                    }
                }
                outv[j * (CZ / 4) + cg] = acc * __int_as_float(m.w);
            }
        };

        #define RUN_CASE(K) case K: run(std::integral_constant<int, K>{}); break;
        switch (icode) {
            RUN_CASE(0)  RUN_CASE(1)  RUN_CASE(2)  RUN_CASE(3)
            RUN_CASE(4)  RUN_CASE(5)  RUN_CASE(6)  RUN_CASE(7)
            RUN_CASE(8)  RUN_CASE(9)  RUN_CASE(10) RUN_CASE(11)
            RUN_CASE(12) RUN_CASE(13) RUN_CASE(14) RUN_CASE(15)
        }
        #undef RUN_CASE
    }
}

extern "C" void kernel_launch(void* const* d_in, const int* in_sizes, int n_in,
                              void* d_out, int out_size, void* d_ws, size_t ws_size,
                              hipStream_t stream) {
    const int*   aatype = (const int*)d_in[0];
    const float* coords = (const float*)d_in[1];
    const int*   tmask  = (const int*)d_in[2];
    const int*   rmask  = (const int*)d_in[3];
    const float* weight = (const float*)d_in[4];
    const float* bias   = (const float*)d_in[5];
    float* out = (float*)d_out;

    dim3 grid(256);
    dim3 block(512);
    tpe_kernel<<<grid, block, 0, stream>>>(aatype, coords, tmask, rmask, weight, bias, out);
}

// Round 7
// 32.741 us; speedup vs baseline: 1.4059x; 1.2007x over previous
//
#include <hip/hip_runtime.h>
#include <cstddef>
#include <type_traits>

#define BB 2
#define TT 4
#define LL 384
#define CZ 128
#define NBINS 39
#define NBOUND 38

typedef float f32x4 __attribute__((ext_vector_type(4)));

// One block per (b, i). 512 threads, 3 blocks/CU target.
// LDS: Wd 19.5K + Wj 10.5K + meta 6K = 36 KB.
// Prologue: issue staging loads -> compute meta (hides latency) -> commit -> barrier.
__global__ __launch_bounds__(512, 6) void tpe_kernel(
    const int*   __restrict__ aatype,   // [B,T,L] int32
    const float* __restrict__ coords,   // [B,T,L,3] f32
    const int*   __restrict__ tmask,    // [B,T,L] bool->int32
    const int*   __restrict__ rmask,    // [B,L] bool->int32
    const float* __restrict__ weight,   // [82,128] f32
    const float* __restrict__ bias,     // [128] f32
    float*       __restrict__ out)      // [B,L,L,128] f32
{
    __shared__ float Wd_sh[NBINS * CZ];  // raw rows 0..38
    __shared__ float Wj_sh[21 * CZ];     // rows 61..81
    __shared__ int4  meta_sh[LL];        // {pk01, pk23, 0, scale}; pk: bin|aa<<6|act<<11

    const int bi  = blockIdx.x;
    const int b   = bi / LL;
    const int i   = bi - b * LL;
    const int tid = threadIdx.x;
    const int bT  = b * TT;
    const int cg  = tid & 31;

    // ---- Issue staging loads into registers (commit deferred) ----
    // Flat float4 range: [0,1248) = Wd rows 0..38; [1248,1920) = Wj rows 61..81.
    const float4* wsrc = (const float4*)weight;
    float4 st0 = wsrc[tid];
    float4 st1 = wsrc[tid + 512];
    const int idx2 = tid + 1024;
    float4 st2 = (idx2 < 1248) ? wsrc[idx2] : wsrc[61 * 32 + idx2 - 1248];
    float4 st3;
    if (tid < 384) st3 = wsrc[61 * 32 + tid + 288];   // flat 1536..1919 -> wj 288..671

    // ---- Prefetch per-i row data (before barrier; hides under meta) ----
    const f32x4* W4 = (const f32x4*)weight;
    const f32x4* B4 = (const f32x4*)bias;
    f32x4 wmb = W4[NBINS * (CZ / 4) + cg] + B4[cg];   // W_m + bias
    int icode = 0;
    f32x4 pr[TT];
    #pragma unroll
    for (int t = 0; t < TT; ++t) {
        icode |= (tmask[(bT + t) * LL + i] != 0) << t;
        int aa = aatype[(bT + t) * LL + i];
        aa = min(max(aa, 0), 20);
        pr[t] = W4[(NBINS + 1 + aa) * (CZ / 4) + cg];   // W_i row
    }
    #pragma unroll
    for (int t = 0; t < TT; ++t) pr[t] += wmb;          // pr = W_i + W_m + bias

    // ---- Per-j meta (one thread per j) while staging loads fly ----
    if (tid < LL) {
        #pragma clang fp contract(off)
        const int j  = tid;
        const int ri = rmask[b * LL + i];
        unsigned pks[TT] = {0, 0, 0, 0};
        int cnt = 0;
        #pragma unroll
        for (int t = 0; t < TT; ++t) {
            if (icode & (1 << t)) {                 // wave-uniform branch
                const int base = (bT + t) * LL;
                if (tmask[base + j] != 0) {
                    const float* ci = coords + (size_t)(base + i) * 3;
                    const float* cj = coords + (size_t)(base + j) * 3;
                    float dx = ci[0] - cj[0];
                    float dy = ci[1] - cj[1];
                    float dz = ci[2] - cj[2];
                    float s  = dx * dx + dy * dy;   // numpy order ((x+y)+z)
                    s = s + dz * dz;
                    float d = sqrtf(s);             // IEEE sqrt
                    int bin = 0;
                    #pragma unroll
                    for (int k = 0; k < NBOUND; ++k) {
                        // folded at compile time; matches np.linspace(f64).astype(f32)
                        float bnd = (float)(3.25 + (double)k * (47.5 / 37.0));
                        bin += (d > bnd) ? 1 : 0;   // searchsorted side='left'
                    }
                    int aa = aatype[base + j];
                    aa = min(max(aa, 0), 20);
                    pks[t] = (unsigned)(bin | (aa << 6) | (1 << 11));
                    ++cnt;
                }
            }
        }
        float scale = (ri != 0 && rmask[b * LL + j] != 0)
                      ? 1.0f / fmaxf((float)cnt, 1.0f) : 0.0f;
        int4 m;
        m.x = (int)(pks[0] | (pks[1] << 16));
        m.y = (int)(pks[2] | (pks[3] << 16));
        m.z = 0;
        m.w = __float_as_int(scale);
        meta_sh[j] = m;
    }

    // ---- Commit staged weights to LDS ----
    {
        float4* wd = (float4*)Wd_sh;
        float4* wj = (float4*)Wj_sh;
        wd[tid] = st0;
        wd[tid + 512] = st1;
        if (idx2 < 1248) wd[idx2] = st2; else wj[idx2 - 1248] = st2;
        if (tid < 384) wj[tid + 288] = st3;
    }
    __syncthreads();

    // ---- Phase 2: switch-specialized, branch-free (R4 structure) ----
    const int jj = tid >> 5;       // 0..15
    const f32x4* Wd4 = (const f32x4*)Wd_sh;
    const f32x4* Wj4 = (const f32x4*)Wj_sh;
    f32x4* outv = (f32x4*)(out + (size_t)(b * LL + i) * LL * CZ);

    auto run = [&](auto cmc) {
        constexpr int CM = decltype(cmc)::value;
        #pragma unroll 2
        for (int j = jj; j < LL; j += 16) {
            int4 m = meta_sh[j];                    // broadcast b128
            f32x4 acc = {0.f, 0.f, 0.f, 0.f};
            #pragma unroll
            for (int t = 0; t < TT; ++t) {
                if (CM & (1 << t)) {
                    unsigned h = (unsigned)(t < 2 ? m.x : m.y);
                    unsigned pk = (h >> ((t & 1) * 16)) & 0xFFFFu;
                    f32x4 a = Wd4[(pk & 63u) * (CZ / 4) + cg];        // W_d[bin]
                    f32x4 c = Wj4[((pk >> 6) & 31u) * (CZ / 4) + cg]; // W_j[aa]
                    float mt = (float)((pk >> 11) & 1u);
                    acc += (a + c + pr[t]) * mt;
                }
            }
            outv[j * (CZ / 4) + cg] = acc * __int_as_float(m.w);
        }
    };

    #define RUN_CASE(K) case K: run(std::integral_constant<int, K>{}); break;
    switch (icode) {
        RUN_CASE(0)  RUN_CASE(1)  RUN_CASE(2)  RUN_CASE(3)
        RUN_CASE(4)  RUN_CASE(5)  RUN_CASE(6)  RUN_CASE(7)
        RUN_CASE(8)  RUN_CASE(9)  RUN_CASE(10) RUN_CASE(11)
        RUN_CASE(12) RUN_CASE(13) RUN_CASE(14) RUN_CASE(15)
    }
    #undef RUN_CASE
}

extern "C" void kernel_launch(void* const* d_in, const int* in_sizes, int n_in,
                              void* d_out, int out_size, void* d_ws, size_t ws_size,
                              hipStream_t stream) {
    const int*   aatype = (const int*)d_in[0];
    const float* coords = (const float*)d_in[1];
    const int*   tmask  = (const int*)d_in[2];
    const int*   rmask  = (const int*)d_in[3];
    const float* weight = (const float*)d_in[4];
    const float* bias   = (const float*)d_in[5];
    float* out = (float*)d_out;

    dim3 grid(BB * LL);
    dim3 block(512);
    tpe_kernel<<<grid, block, 0, stream>>>(aatype, coords, tmask, rmask, weight, bias, out);
}

// Round 8
// 32.248 us; speedup vs baseline: 1.4273x; 1.0153x over previous
//
#include <hip/hip_runtime.h>
#include <cstddef>
#include <type_traits>

#define BB 2
#define TT 4
#define LL 384
#define CZ 128
#define NBINS 39
#define NBOUND 38

typedef float f32x4 __attribute__((ext_vector_type(4)));

// One block per (b, i). 512 threads.
// LDS: Wd 19.5K + Wj 10.5K + meta 6K = 36 KB.
// Phase 2 gathers are guarded by the per-j active bit (uniform within each
// 32-lane j-group) -> skip LDS+VALU for inactive (t,j) terms.
__global__ __launch_bounds__(512) void tpe_kernel(
    const int*   __restrict__ aatype,   // [B,T,L] int32
    const float* __restrict__ coords,   // [B,T,L,3] f32
    const int*   __restrict__ tmask,    // [B,T,L] bool->int32
    const int*   __restrict__ rmask,    // [B,L] bool->int32
    const float* __restrict__ weight,   // [82,128] f32
    const float* __restrict__ bias,     // [128] f32
    float*       __restrict__ out)      // [B,L,L,128] f32
{
    __shared__ float Wd_sh[NBINS * CZ];  // raw rows 0..38
    __shared__ float Wj_sh[21 * CZ];     // rows 61..81
    __shared__ int4  meta_sh[LL];        // {pk01, pk23, 0, scale}; pk: bin|aa<<6|act<<11

    const int bi  = blockIdx.x;
    const int b   = bi / LL;
    const int i   = bi - b * LL;
    const int tid = threadIdx.x;
    const int bT  = b * TT;
    const int cg  = tid & 31;

    // ---- Issue staging loads into registers (commit deferred) ----
    // Flat float4 range: [0,1248) = Wd rows 0..38; [1248,1920) = Wj rows 61..81.
    const float4* wsrc = (const float4*)weight;
    float4 st0 = wsrc[tid];
    float4 st1 = wsrc[tid + 512];
    const int idx2 = tid + 1024;
    float4 st2 = (idx2 < 1248) ? wsrc[idx2] : wsrc[61 * 32 + idx2 - 1248];
    float4 st3;
    if (tid < 384) st3 = wsrc[61 * 32 + tid + 288];   // flat 1536..1919 -> wj 288..671

    // ---- Prefetch per-i row data (hides under meta compute) ----
    const f32x4* W4 = (const f32x4*)weight;
    const f32x4* B4 = (const f32x4*)bias;
    f32x4 wmb = W4[NBINS * (CZ / 4) + cg] + B4[cg];   // W_m + bias
    int icode = 0;
    f32x4 pr[TT];
    #pragma unroll
    for (int t = 0; t < TT; ++t) {
        icode |= (tmask[(bT + t) * LL + i] != 0) << t;
        int aa = aatype[(bT + t) * LL + i];
        aa = min(max(aa, 0), 20);
        pr[t] = W4[(NBINS + 1 + aa) * (CZ / 4) + cg];   // W_i row
    }
    #pragma unroll
    for (int t = 0; t < TT; ++t) pr[t] += wmb;          // pr = W_i + W_m + bias

    // ---- Per-j meta (one thread per j) while staging loads fly ----
    if (tid < LL) {
        #pragma clang fp contract(off)
        const int j  = tid;
        const int ri = rmask[b * LL + i];
        unsigned pks[TT] = {0, 0, 0, 0};
        int cnt = 0;
        #pragma unroll
        for (int t = 0; t < TT; ++t) {
            if (icode & (1 << t)) {                 // wave-uniform branch
                const int base = (bT + t) * LL;
                if (tmask[base + j] != 0) {
                    const float* ci = coords + (size_t)(base + i) * 3;
                    const float* cj = coords + (size_t)(base + j) * 3;
                    float dx = ci[0] - cj[0];
                    float dy = ci[1] - cj[1];
                    float dz = ci[2] - cj[2];
                    float s  = dx * dx + dy * dy;   // numpy order ((x+y)+z)
                    s = s + dz * dz;
                    float d = sqrtf(s);             // IEEE sqrt
                    int bin = 0;
                    #pragma unroll
                    for (int k = 0; k < NBOUND; ++k) {
                        // folded at compile time; matches np.linspace(f64).astype(f32)
                        float bnd = (float)(3.25 + (double)k * (47.5 / 37.0));
                        bin += (d > bnd) ? 1 : 0;   // searchsorted side='left'
                    }
                    int aa = aatype[base + j];
                    aa = min(max(aa, 0), 20);
                    pks[t] = (unsigned)(bin | (aa << 6) | (1 << 11));
                    ++cnt;
                }
            }
        }
        float scale = (ri != 0 && rmask[b * LL + j] != 0)
                      ? 1.0f / fmaxf((float)cnt, 1.0f) : 0.0f;
        int4 m;
        m.x = (int)(pks[0] | (pks[1] << 16));
        m.y = (int)(pks[2] | (pks[3] << 16));
        m.z = 0;
        m.w = __float_as_int(scale);
        meta_sh[j] = m;
    }

    // ---- Commit staged weights to LDS ----
    {
        float4* wd = (float4*)Wd_sh;
        float4* wj = (float4*)Wj_sh;
        wd[tid] = st0;
        wd[tid + 512] = st1;
        if (idx2 < 1248) wd[idx2] = st2; else wj[idx2 - 1248] = st2;
        if (tid < 384) wj[tid + 288] = st3;
    }
    __syncthreads();

    // ---- Phase 2: switch-specialized; gathers guarded by per-j active bit ----
    const int jj = tid >> 5;       // 0..15
    const f32x4* Wd4 = (const f32x4*)Wd_sh;
    const f32x4* Wj4 = (const f32x4*)Wj_sh;
    f32x4* outv = (f32x4*)(out + (size_t)(b * LL + i) * LL * CZ);

    auto run = [&](auto cmc) {
        constexpr int CM = decltype(cmc)::value;
        #pragma unroll 4
        for (int j = jj; j < LL; j += 16) {
            int4 m = meta_sh[j];                    // broadcast b128
            f32x4 acc = {0.f, 0.f, 0.f, 0.f};
            #pragma unroll
            for (int t = 0; t < TT; ++t) {
                if (CM & (1 << t)) {
                    unsigned h = (unsigned)(t < 2 ? m.x : m.y);
                    unsigned pk = (h >> ((t & 1) * 16)) & 0xFFFFu;
                    if (pk & 2048u) {               // uniform per 32-lane j-group
                        f32x4 a = Wd4[(pk & 63u) * (CZ / 4) + cg];        // W_d[bin]
                        f32x4 c = Wj4[((pk >> 6) & 31u) * (CZ / 4) + cg]; // W_j[aa]
                        acc += a + c + pr[t];
                    }
                }
            }
            outv[j * (CZ / 4) + cg] = acc * __int_as_float(m.w);
        }
    };

    #define RUN_CASE(K) case K: run(std::integral_constant<int, K>{}); break;
    switch (icode) {
        RUN_CASE(0)  RUN_CASE(1)  RUN_CASE(2)  RUN_CASE(3)
        RUN_CASE(4)  RUN_CASE(5)  RUN_CASE(6)  RUN_CASE(7)
        RUN_CASE(8)  RUN_CASE(9)  RUN_CASE(10) RUN_CASE(11)
        RUN_CASE(12) RUN_CASE(13) RUN_CASE(14) RUN_CASE(15)
    }
    #undef RUN_CASE
}

extern "C" void kernel_launch(void* const* d_in, const int* in_sizes, int n_in,
                              void* d_out, int out_size, void* d_ws, size_t ws_size,
                              hipStream_t stream) {
    const int*   aatype = (const int*)d_in[0];
    const float* coords = (const float*)d_in[1];
    const int*   tmask  = (const int*)d_in[2];
    const int*   rmask  = (const int*)d_in[3];
    const float* weight = (const float*)d_in[4];
    const float* bias   = (const float*)d_in[5];
    float* out = (float*)d_out;

    dim3 grid(BB * LL);
    dim3 block(512);
    tpe_kernel<<<grid, block, 0, stream>>>(aatype, coords, tmask, rmask, weight, bias, out);
}